// Round 1
// baseline (48.038 us; speedup 1.0000x reference)
//
#include <hip/hip_runtime.h>

// Problem constants
#define BB     4096
#define NNODE  177
#define NSUB   36
#define KN     6
#define HH     128
#define OBSD   500
// Fused-K for U-GEMM: 500 (obs) + 128 (sub) = 628, padded to 640 (20x32 MFMA steps),
// LDS row stride 648 (pad +8 bf16 so row stride % 128B != 0 -> conflict-free b128 frag reads)
#define KU_MFMA 640
#define KU_LDS  648
#define KN_LDS  136   // node K stride: 128 + 8 pad

typedef unsigned short ushort_t;
typedef __attribute__((ext_vector_type(4))) float f32x4;
typedef __attribute__((ext_vector_type(8))) short s16x8;

#define MFMA16(a, b, c) __builtin_amdgcn_mfma_f32_16x16x32_bf16((a), (b), (c), 0, 0, 0)

// ws layout (bytes)
#define WS_WFT   0                    // ushort[128*640]  = 163840 B
#define WS_W1CT  163840               // ushort[128*128]  =  32768 B
#define WS_BIAS  196608               // float[128]       =    512 B

__device__ __forceinline__ ushort_t f2bf(float f) {
    unsigned u = __float_as_uint(f);
    u += 0x7FFFu + ((u >> 16) & 1u);   // round-to-nearest-even
    return (ushort_t)(u >> 16);
}

// ---------------------------------------------------------------------------
// Prep: WfullT[j][k] bf16 (k<500: (W_proj@W1a)^T, 500..627: W1b^T, 628..639: 0),
//       W1cT[j][k] bf16, biasw[j] = b_proj@W1a
// ---------------------------------------------------------------------------
__global__ void __launch_bounds__(256) k_prep(const float* __restrict__ Wproj,
                                              const float* __restrict__ bproj,
                                              const float* __restrict__ W1,
                                              ushort_t* __restrict__ WfT,
                                              ushort_t* __restrict__ W1cT,
                                              float* __restrict__ biasw) {
    int flat = blockIdx.x * 256 + threadIdx.x;
    if (flat < 128 * 640) {
        int j = flat & 127, k = flat >> 7;       // j coalesced for W1 reads
        float acc = 0.f;
        if (k < 500) {
            #pragma unroll 4
            for (int i = 0; i < 128; ++i) acc += Wproj[k * 128 + i] * W1[i * 128 + j];
        } else if (k < 628) {
            acc = W1[(128 + (k - 500)) * 128 + j];
        }
        WfT[j * 640 + k] = f2bf(acc);
    } else if (flat < 128 * 640 + 128 * 128) {
        int o = flat - 128 * 640;
        int j = o & 127, k = o >> 7;
        W1cT[j * 128 + k] = f2bf(W1[(256 + k) * 128 + j]);
    } else if (flat < 128 * 640 + 128 * 128 + 128) {
        int j = flat - (128 * 640 + 128 * 128);
        float acc = 0.f;
        for (int i = 0; i < 128; ++i) acc += bproj[i] * W1[i * 128 + j];
        biasw[j] = acc;
    }
}

// ---------------------------------------------------------------------------
// Main: per block = 8 batch elems. Stage gathered inputs as bf16 in LDS,
// MFMA U-GEMM (K=640) + V-GEMM (K=128), combine into h[8][6][128] f32 in LDS,
// then fused 2-layer GAT with 32 lanes per batch elem.
// ---------------------------------------------------------------------------
__global__ void __launch_bounds__(256, 2) k_main(
    const float* __restrict__ org_obs, const float* __restrict__ node_emb,
    const float* __restrict__ subst,   const int* __restrict__ sub_choice,
    const int* __restrict__ sub_map,   const ushort_t* __restrict__ WfT,
    const ushort_t* __restrict__ W1cT, const float* __restrict__ biasw,
    const float* __restrict__ a_src1,  const float* __restrict__ a_dst1,
    const float* __restrict__ b1,      const float* __restrict__ W2,
    const float* __restrict__ a_src2,  const float* __restrict__ a_dst2,
    const float* __restrict__ b2,      float* __restrict__ out) {

    // LDS: region0 = union(obs staging 16x648 bf16 = 20736 B, h 8x6x128 f32 = 24576 B)
    //      region1 = nodes 6x16x136 bf16 = 26112 B; meta = 224 B
    __shared__ __align__(16) char smem[24576 + 26112 + 256];
    ushort_t* s_obs   = (ushort_t*)smem;               // [16][648]
    float*    s_h     = (float*)smem;                  // [8][6][128]
    ushort_t* s_nodes = (ushort_t*)(smem + 24576);     // [6][16][136]
    int*      s_sub   = (int*)(smem + 24576 + 26112);  // [8]
    int*      s_elem  = s_sub + 8;                     // [8][6]

    const int t   = threadIdx.x;
    const int gb0 = blockIdx.x * 8;

    if (t < 8) s_sub[t] = sub_choice[gb0 + t];
    __syncthreads();

    {   // obs + gathered substation staging (rows 0..7 real, 8..15 zero)
        int b = t >> 5, l = t & 31;
        const float* orow = org_obs + (gb0 + b) * OBSD;
        const float* srow = subst + ((gb0 + b) * NSUB + s_sub[b]) * HH;
        for (int k = l; k < KU_LDS; k += 32) {
            float v = (k < OBSD) ? orow[k] : (k < OBSD + HH ? srow[k - OBSD] : 0.f);
            s_obs[b * KU_LDS + k] = f2bf(v);
        }
        for (int k = l; k < KU_LDS; k += 32) s_obs[(8 + b) * KU_LDS + k] = 0;
    }
    if (t < 64) {
        int b = t >> 3, s = t & 7;
        if (s < 6) s_elem[b * 6 + s] = sub_map[s_sub[b] * KN + s];
    }
    __syncthreads();

    {   // gathered node staging
        int b = t >> 5, l = t & 31;
        #pragma unroll
        for (int s = 0; s < 6; ++s) {
            const float* nrow = node_emb + ((gb0 + b) * NNODE + s_elem[b * 6 + s]) * HH;
            #pragma unroll
            for (int k = l; k < 128; k += 32) {
                s_nodes[(s * 16 + b) * KN_LDS + k]     = f2bf(nrow[k]);
                s_nodes[(s * 16 + 8 + b) * KN_LDS + k] = 0;
            }
        }
    }
    __syncthreads();

    const int ln = t & 63, wv = t >> 6;
    const int r16 = ln & 15, g = ln >> 4;
    const int colA = wv * 32 + r16, colB = colA + 16;   // this wave owns cols [wv*32, wv*32+32)

    // U-phase: u[b][j] over K=640, A from LDS, B-frags straight from L2
    f32x4 u0 = {0.f, 0.f, 0.f, 0.f}, u1 = {0.f, 0.f, 0.f, 0.f};
    #pragma unroll
    for (int kk = 0; kk < KU_MFMA / 32; ++kk) {
        s16x8 af  = *(const s16x8*)&s_obs[r16 * KU_LDS + kk * 32 + g * 8];
        s16x8 bf0 = *(const s16x8*)&WfT[colA * 640 + kk * 32 + g * 8];
        s16x8 bf1 = *(const s16x8*)&WfT[colB * 640 + kk * 32 + g * 8];
        u0 = MFMA16(af, bf0, u0);
        u1 = MFMA16(af, bf1, u1);
    }

    // V-phase: v[s][b][j] over K=128
    f32x4 v0[6], v1[6];
    #pragma unroll
    for (int s = 0; s < 6; ++s) {
        v0[s] = (f32x4){0.f, 0.f, 0.f, 0.f};
        v1[s] = (f32x4){0.f, 0.f, 0.f, 0.f};
    }
    #pragma unroll
    for (int kk = 0; kk < 4; ++kk) {
        s16x8 bf0 = *(const s16x8*)&W1cT[colA * 128 + kk * 32 + g * 8];
        s16x8 bf1 = *(const s16x8*)&W1cT[colB * 128 + kk * 32 + g * 8];
        #pragma unroll
        for (int s = 0; s < 6; ++s) {
            s16x8 af = *(const s16x8*)&s_nodes[(s * 16 + r16) * KN_LDS + kk * 32 + g * 8];
            v0[s] = MFMA16(af, bf0, v0[s]);
            v1[s] = MFMA16(af, bf1, v1[s]);
        }
    }
    __syncthreads();   // all LDS reads done -> reuse region0 as s_h

    {   // h[b][s][j] = u + v + (b_proj @ W1a)[j]   (D map: col=lane&15, row=(lane>>4)*4+reg)
        float biasA = biasw[colA], biasB = biasw[colB];
        #pragma unroll
        for (int r = 0; r < 4; ++r) {
            int b = g * 4 + r;
            if (b < 8) {
                #pragma unroll
                for (int s = 0; s < 6; ++s) {
                    s_h[(b * 6 + s) * 128 + colA] = u0[r] + v0[s][r] + biasA;
                    s_h[(b * 6 + s) * 128 + colB] = u1[r] + v1[s][r] + biasB;
                }
            }
        }
    }
    __syncthreads();

    // ---- fused GAT: 32 lanes per batch elem; lane holds channels c = r*32 + l32 (head = r)
    {
        const int b = t >> 5, l32 = t & 31;
        float hr[6][4];
        #pragma unroll
        for (int s = 0; s < 6; ++s)
            #pragma unroll
            for (int r = 0; r < 4; ++r)
                hr[s][r] = s_h[(b * 6 + s) * 128 + r * 32 + l32];

        float asr[4], adr[4], b1r[4], w2r[4];
        #pragma unroll
        for (int r = 0; r < 4; ++r) {
            asr[r] = a_src1[r * 32 + l32];
            adr[r] = a_dst1[r * 32 + l32];
            b1r[r] = b1[r * 32 + l32];
            w2r[r] = W2[r * 32 + l32];
        }

        // e_src/e_dst: per (s,head) 32-wide dot via butterfly (all lanes get result)
        float es[6][4], ed[6][4];
        #pragma unroll
        for (int s = 0; s < 6; ++s)
            #pragma unroll
            for (int r = 0; r < 4; ++r) {
                float ps = hr[s][r] * asr[r];
                float pd = hr[s][r] * adr[r];
                #pragma unroll
                for (int m = 16; m >= 1; m >>= 1) {
                    ps += __shfl_xor(ps, m, 32);
                    pd += __shfl_xor(pd, m, 32);
                }
                es[s][r] = ps; ed[s][r] = pd;
            }

        // layer-1 softmax + aggregation + bias + ELU (redundant per lane — cheap)
        float h1v[6][4];
        #pragma unroll
        for (int i = 0; i < 6; ++i)
            #pragma unroll
            for (int r = 0; r < 4; ++r) {
                float ev[6], mx = -1e30f;
                #pragma unroll
                for (int j = 0; j < 6; ++j) {
                    float e = ed[i][r] + es[j][r];
                    e = (e > 0.f) ? e : 0.2f * e;     // leaky_relu(0.2)
                    ev[j] = e; mx = fmaxf(mx, e);
                }
                float ssum = 0.f, acc = 0.f;
                #pragma unroll
                for (int j = 0; j < 6; ++j) {
                    float ex = __expf(ev[j] - mx);
                    ssum += ex; acc += ex * hr[j][r];
                }
                float o = acc / ssum + b1r[r];
                h1v[i][r] = (o > 0.f) ? o : (__expf(o) - 1.f);   // ELU
            }

        // layer 2: scalar per node
        float hh[6];
        #pragma unroll
        for (int s = 0; s < 6; ++s) {
            float p = h1v[s][0] * w2r[0] + h1v[s][1] * w2r[1] +
                      h1v[s][2] * w2r[2] + h1v[s][3] * w2r[3];
            #pragma unroll
            for (int m = 16; m >= 1; m >>= 1) p += __shfl_xor(p, m, 32);
            hh[s] = p;
        }

        float as2 = a_src2[0], ad2 = a_dst2[0], bb2 = b2[0];
        #pragma unroll
        for (int i = 0; i < 6; ++i) {
            float ev[6], mx = -1e30f;
            #pragma unroll
            for (int j = 0; j < 6; ++j) {
                float e = hh[i] * ad2 + hh[j] * as2;
                e = (e > 0.f) ? e : 0.2f * e;
                ev[j] = e; mx = fmaxf(mx, e);
            }
            float ssum = 0.f, acc = 0.f;
            #pragma unroll
            for (int j = 0; j < 6; ++j) {
                float ex = __expf(ev[j] - mx);
                ssum += ex; acc += ex * hh[j];
            }
            if (l32 == 0) out[(gb0 + b) * 6 + i] = acc / ssum + bb2;
        }
    }
}

extern "C" void kernel_launch(void* const* d_in, const int* in_sizes, int n_in,
                              void* d_out, int out_size, void* d_ws, size_t ws_size,
                              hipStream_t stream) {
    const float* org_obs    = (const float*)d_in[0];
    const float* node_emb   = (const float*)d_in[1];
    const float* subst      = (const float*)d_in[2];
    const int*   sub_choice = (const int*)d_in[3];
    const int*   sub_map    = (const int*)d_in[4];
    const float* Wproj      = (const float*)d_in[5];
    const float* bproj      = (const float*)d_in[6];
    const float* W1         = (const float*)d_in[7];
    const float* a_src1     = (const float*)d_in[8];
    const float* a_dst1     = (const float*)d_in[9];
    const float* b1         = (const float*)d_in[10];
    const float* W2         = (const float*)d_in[11];
    const float* a_src2     = (const float*)d_in[12];
    const float* a_dst2     = (const float*)d_in[13];
    const float* b2         = (const float*)d_in[14];

    ushort_t* WfT   = (ushort_t*)((char*)d_ws + WS_WFT);
    ushort_t* W1cT  = (ushort_t*)((char*)d_ws + WS_W1CT);
    float*    biasw = (float*)((char*)d_ws + WS_BIAS);
    float*    outp  = (float*)d_out;

    hipLaunchKernelGGL(k_prep, dim3(385), dim3(256), 0, stream,
                       Wproj, bproj, W1, WfT, W1cT, biasw);
    hipLaunchKernelGGL(k_main, dim3(BB / 8), dim3(256), 0, stream,
                       org_obs, node_emb, subst, sub_choice, sub_map,
                       WfT, W1cT, biasw, a_src1, a_dst1, b1, W2,
                       a_src2, a_dst2, b2, outp);
}

// Round 2
// 36.651 us; speedup vs baseline: 1.3107x; 1.3107x over previous
//
#include <hip/hip_runtime.h>

// Problem constants
#define BB     4096
#define NNODE  177
#define NSUB   36
#define KN     6
#define HH     128
#define OBSD   500
#define TB     16          // batches per block
#define NTHR   512         // 8 waves
#define KU_LDS 648         // obs+sub K (628) padded; stride%128B!=0
#define KN_LDS 136         // node K stride: 128 + 8 pad
// Extended N: 128 h-channels + 4 e_src heads + 4 e_dst heads (+pad) = 144 rows
#define NEXT   144

typedef unsigned short ushort_t;
typedef __attribute__((ext_vector_type(4))) float f32x4;
typedef __attribute__((ext_vector_type(8))) short s16x8;
typedef __attribute__((ext_vector_type(4))) unsigned short u16x4;

#define MFMA16(a, b, c) __builtin_amdgcn_mfma_f32_16x16x32_bf16((a), (b), (c), 0, 0, 0)

// ws layout (bytes)
#define WS_WFT   0          // ushort[144*640] = 184320
#define WS_W1CT  184320     // ushort[144*128] =  36864
#define WS_BIAS  221184     // float[144]      =    576

__device__ __forceinline__ ushort_t f2bf(float f) {
    unsigned u = __float_as_uint(f);
    u += 0x7FFFu + ((u >> 16) & 1u);   // RNE
    return (ushort_t)(u >> 16);
}
__device__ __forceinline__ u16x4 f2bf4(float4 v) {
    u16x4 o; o.x = f2bf(v.x); o.y = f2bf(v.y); o.z = f2bf(v.z); o.w = f2bf(v.w);
    return o;
}

// ---------------------------------------------------------------------------
// Prep. Rows j<128 of WfT: [Wf=W_proj@W1a ; W1b]^T (K=640). Rows 128+e
// (e=0..3 src head e, e=4..7 dst head e-4): same GEMM folded with a-vectors,
// so e_src/e_dst come out of the main MFMA as extra columns. Same for W1cT.
// biasw[0..127] = b_proj@W1a, biasw[128+e] = its a-fold.
// ---------------------------------------------------------------------------
__global__ void __launch_bounds__(256) k_prep(const float* __restrict__ Wproj,
                                              const float* __restrict__ bproj,
                                              const float* __restrict__ W1,
                                              const float* __restrict__ a_src1,
                                              const float* __restrict__ a_dst1,
                                              ushort_t* __restrict__ WfT,
                                              ushort_t* __restrict__ W1cT,
                                              float* __restrict__ biasw) {
    const int blk = blockIdx.x, t = threadIdx.x;
    if (blk < 320) {                       // WfT main rows: 128*640 elems
        int flat = blk * 256 + t;
        int j = flat & 127, k = flat >> 7;
        float acc = 0.f;
        if (k < 500) {
            #pragma unroll 4
            for (int i = 0; i < 128; ++i) acc += Wproj[k * 128 + i] * W1[i * 128 + j];
        } else if (k < 628) {
            acc = W1[(128 + (k - 500)) * 128 + j];
        }
        WfT[j * 640 + k] = f2bf(acc);
    } else if (blk < 384) {                // W1cT main rows: 128*128
        int o = (blk - 320) * 256 + t;
        int j = o & 127, k = o >> 7;
        W1cT[j * 128 + k] = f2bf(W1[(256 + k) * 128 + j]);
    } else if (blk < 392) {                // WfT e-row (one per block)
        int e = blk - 384;
        int r = (e < 4) ? e : e - 4;
        const float* av = ((e < 4) ? a_src1 : a_dst1) + r * 32;
        __shared__ float s_we[384];
        for (int i = t; i < 384; i += 256) {
            float acc = 0.f;
            #pragma unroll
            for (int f = 0; f < 32; ++f) acc += W1[i * 128 + r * 32 + f] * av[f];
            s_we[i] = acc;
        }
        __syncthreads();
        for (int k = t; k < 640; k += 256) {
            float acc = 0.f;
            if (k < 500) {
                #pragma unroll 4
                for (int i = 0; i < 128; ++i) acc += Wproj[k * 128 + i] * s_we[i];
            } else if (k < 628) {
                acc = s_we[128 + (k - 500)];
            }
            WfT[(128 + e) * 640 + k] = f2bf(acc);
        }
    } else {                               // blk==392: W1cT e-rows + biasw
        __shared__ float s_w[384][8];
        for (int it = t; it < 2048; it += 256) {   // rows [0,128)∪[256,384) × 8
            int e = it & 7, i2 = it >> 3;
            int i = (i2 < 128) ? i2 : (i2 + 128);
            int r = (e < 4) ? e : e - 4;
            const float* av = ((e < 4) ? a_src1 : a_dst1) + r * 32;
            float acc = 0.f;
            #pragma unroll
            for (int f = 0; f < 32; ++f) acc += W1[i * 128 + r * 32 + f] * av[f];
            s_w[i][e] = acc;
        }
        __syncthreads();
        for (int it = t; it < 1024; it += 256) {
            int e = it >> 7, k = it & 127;
            W1cT[(128 + e) * 128 + k] = f2bf(s_w[256 + k][e]);
        }
        if (t < 128) {
            float acc = 0.f;
            for (int i = 0; i < 128; ++i) acc += bproj[i] * W1[i * 128 + t];
            biasw[t] = acc;
        } else if (t < 136) {
            int e = t - 128;
            float acc = 0.f;
            for (int i = 0; i < 128; ++i) acc += bproj[i] * s_w[i][e];
            biasw[t] = acc;
        }
    }
}

// ---------------------------------------------------------------------------
// Main: block = 16 batch elems, 8 waves. Wave w owns cols [16w,16w+16);
// wave 0 additionally computes the e-tile (cols 128..135 = es/ed per head).
// h stays in MFMA fragments (lane: 1 col × 4 batches × 6 nodes) — layer-1
// aggregation over j is in-lane; alphas cooperative in LDS.
// ---------------------------------------------------------------------------
__global__ void __launch_bounds__(NTHR) k_main(
    const float* __restrict__ org_obs, const float* __restrict__ node_emb,
    const float* __restrict__ subst,   const int* __restrict__ sub_choice,
    const int* __restrict__ sub_map,   const ushort_t* __restrict__ WfT,
    const ushort_t* __restrict__ W1cT, const float* __restrict__ biasw,
    const float* __restrict__ b1,      const float* __restrict__ W2,
    const float* __restrict__ a_src2,  const float* __restrict__ a_dst2,
    const float* __restrict__ b2,      float* __restrict__ out) {

    // LDS: [0,20736)      s_obs [16][648] bf16  — later alphas/p/hh
    //      [20736,46848)  s_nodes [6][16][136] bf16
    //      [46848,49920)  s_e [16][6][8] f32
    __shared__ __align__(16) char smem[49920];
    ushort_t* s_obs   = (ushort_t*)smem;
    ushort_t* s_nodes = (ushort_t*)(smem + 20736);
    float*    s_e     = (float*)(smem + 46848);
    float*    s_alpha = (float*)smem;                  // [16][6][4][6] = 9216 B
    float*    s_p     = (float*)(smem + 9216);         // [8][16][6]    = 3072 B
    float*    s_hh    = (float*)(smem + 12288);        // [16][6]       =  384 B

    const int t   = threadIdx.x;
    const int gb0 = blockIdx.x * TB;
    const int b   = t >> 5, l = t & 31;                // staging map: 32 lanes/batch

    // ---- issue ALL global loads early (node gathers ride under U-phase MFMAs)
    float4 oreg[4], sreg, nreg[6];
    {
        const float* orow = org_obs + (size_t)(gb0 + b) * OBSD;
        #pragma unroll
        for (int it = 0; it < 4; ++it) {
            int idx = it * 32 + l;
            if (idx < 125) oreg[it] = ((const float4*)orow)[idx];
        }
        int sub = sub_choice[gb0 + b];
        const float* srow = subst + ((size_t)(gb0 + b) * NSUB + sub) * HH;
        sreg = ((const float4*)srow)[l];
        #pragma unroll
        for (int s = 0; s < 6; ++s) {
            int eid = sub_map[sub * KN + s];
            const float* nrow = node_emb + ((size_t)(gb0 + b) * NNODE + eid) * HH;
            nreg[s] = ((const float4*)nrow)[l];
        }
        // obs+sub -> LDS (U-phase A operand)
        #pragma unroll
        for (int it = 0; it < 4; ++it) {
            int idx = it * 32 + l;
            if (idx < 125) *(u16x4*)&s_obs[b * KU_LDS + idx * 4] = f2bf4(oreg[it]);
        }
        *(u16x4*)&s_obs[b * KU_LDS + 500 + l * 4] = f2bf4(sreg);
        if (l < 5) { u16x4 z = {0, 0, 0, 0}; *(u16x4*)&s_obs[b * KU_LDS + 628 + l * 4] = z; }
    }
    __syncthreads();

    const int w = t >> 6, ln = t & 63, r16 = ln & 15, g = ln >> 4;
    const int col = w * 16 + r16;

    // ---- U-phase (K=640): u[b][col]
    f32x4 u = {0.f, 0.f, 0.f, 0.f};
    #pragma unroll
    for (int kk = 0; kk < 20; ++kk) {
        s16x8 af = *(const s16x8*)&s_obs[r16 * KU_LDS + kk * 32 + g * 8];
        s16x8 bf = *(const s16x8*)&WfT[col * 640 + kk * 32 + g * 8];
        u = MFMA16(af, bf, u);
    }

    // ---- node regs -> LDS (loads have been in flight through U-phase)
    #pragma unroll
    for (int s = 0; s < 6; ++s)
        *(u16x4*)&s_nodes[(s * 16 + b) * KN_LDS + l * 4] = f2bf4(nreg[s]);
    __syncthreads();

    // ---- V-phase (K=128): v[s][b][col]
    f32x4 v[6];
    #pragma unroll
    for (int s = 0; s < 6; ++s) v[s] = (f32x4){0.f, 0.f, 0.f, 0.f};
    #pragma unroll
    for (int kk = 0; kk < 4; ++kk) {
        s16x8 bf = *(const s16x8*)&W1cT[col * 128 + kk * 32 + g * 8];
        #pragma unroll
        for (int s = 0; s < 6; ++s) {
            s16x8 af = *(const s16x8*)&s_nodes[(s * 16 + r16) * KN_LDS + kk * 32 + g * 8];
            v[s] = MFMA16(af, bf, v[s]);
        }
    }

    // h fragments in registers: h[s][reg] at (batch=g*4+reg, col)
    float h[6][4];
    {
        float bw = biasw[col];
        #pragma unroll
        for (int s = 0; s < 6; ++s)
            #pragma unroll
            for (int rg = 0; rg < 4; ++rg) h[s][rg] = u[rg] + v[s][rg] + bw;
    }

    // ---- e-tile (wave 0): es/ed straight out of MFMA extra columns
    if (w == 0) {
        f32x4 ue = {0.f, 0.f, 0.f, 0.f};
        #pragma unroll
        for (int kk = 0; kk < 20; ++kk) {
            s16x8 af = *(const s16x8*)&s_obs[r16 * KU_LDS + kk * 32 + g * 8];
            s16x8 be = *(const s16x8*)&WfT[(128 + r16) * 640 + kk * 32 + g * 8];
            ue = MFMA16(af, be, ue);
        }
        f32x4 ve[6];
        #pragma unroll
        for (int s = 0; s < 6; ++s) ve[s] = (f32x4){0.f, 0.f, 0.f, 0.f};
        #pragma unroll
        for (int kk = 0; kk < 4; ++kk) {
            s16x8 be = *(const s16x8*)&W1cT[(128 + r16) * 128 + kk * 32 + g * 8];
            #pragma unroll
            for (int s = 0; s < 6; ++s) {
                s16x8 af = *(const s16x8*)&s_nodes[(s * 16 + r16) * KN_LDS + kk * 32 + g * 8];
                ve[s] = MFMA16(af, be, ve[s]);
            }
        }
        if (r16 < 8) {     // cols 128..135: [0..3]=e_src head, [4..7]=e_dst head
            float bwe = biasw[128 + r16];
            #pragma unroll
            for (int s = 0; s < 6; ++s)
                #pragma unroll
                for (int rg = 0; rg < 4; ++rg)
                    s_e[((g * 4 + rg) * 6 + s) * 8 + r16] = ue[rg] + ve[s][rg] + bwe;
        }
    }
    __syncthreads();

    // ---- layer-1 alphas, cooperative: thread (b,i) does 4 heads × softmax(6)
    if (t < 96) {
        int bb = t / 6, ii = t - bb * 6;
        #pragma unroll
        for (int r = 0; r < 4; ++r) {
            float edv = s_e[(bb * 6 + ii) * 8 + 4 + r];
            float ev[6], mx = -1e30f;
            #pragma unroll
            for (int j = 0; j < 6; ++j) {
                float e = edv + s_e[(bb * 6 + j) * 8 + r];
                e = (e > 0.f) ? e : 0.2f * e;
                ev[j] = e; mx = fmaxf(mx, e);
            }
            float ex[6], ss = 0.f;
            #pragma unroll
            for (int j = 0; j < 6; ++j) { ex[j] = __expf(ev[j] - mx); ss += ex[j]; }
            float inv = 1.f / ss;
            #pragma unroll
            for (int j = 0; j < 6; ++j)
                s_alpha[((bb * 6 + ii) * 4 + r) * 6 + j] = ex[j] * inv;
        }
    }
    __syncthreads();

    // ---- aggregation (in-lane over j) + b1 + ELU + W2, then 16-lane reduce
    {
        const int rh = col >> 5;          // head of this lane's column
        float b1v = b1[col], w2v = W2[col];
        float pp[6][4];
        #pragma unroll
        for (int i = 0; i < 6; ++i)
            #pragma unroll
            for (int rg = 0; rg < 4; ++rg) {
                int bb = g * 4 + rg;
                float acc = 0.f;
                #pragma unroll
                for (int s = 0; s < 6; ++s)
                    acc += s_alpha[((bb * 6 + i) * 4 + rh) * 6 + s] * h[s][rg];
                float o = acc + b1v;
                o = (o > 0.f) ? o : __expf(o) - 1.f;   // ELU
                pp[i][rg] = o * w2v;
            }
        #pragma unroll
        for (int i = 0; i < 6; ++i)
            #pragma unroll
            for (int rg = 0; rg < 4; ++rg) {
                float p = pp[i][rg];
                p += __shfl_xor(p, 1); p += __shfl_xor(p, 2);
                p += __shfl_xor(p, 4); p += __shfl_xor(p, 8);
                pp[i][rg] = p;
            }
        if (r16 == 0) {
            #pragma unroll
            for (int rg = 0; rg < 4; ++rg)
                #pragma unroll
                for (int i = 0; i < 6; ++i)
                    s_p[(w * 16 + g * 4 + rg) * 6 + i] = pp[i][rg];
        }
    }
    __syncthreads();

    // ---- h2 = h1 @ W2 (combine 8 wave partials)
    if (t < 96) {
        int bb = t / 6, ii = t - bb * 6;
        float hv = 0.f;
        #pragma unroll
        for (int ww = 0; ww < 8; ++ww) hv += s_p[(ww * 16 + bb) * 6 + ii];
        s_hh[bb * 6 + ii] = hv;
    }
    __syncthreads();

    // ---- layer-2 GAT (scalar) + write
    if (t < 96) {
        int bb = t / 6, ii = t - bb * 6;
        float hi = s_hh[bb * 6 + ii];
        float as2v = a_src2[0], ad2v = a_dst2[0];
        float ev[6], hj[6], mx = -1e30f;
        #pragma unroll
        for (int j = 0; j < 6; ++j) {
            hj[j] = s_hh[bb * 6 + j];
            float e = ad2v * hi + as2v * hj[j];
            e = (e > 0.f) ? e : 0.2f * e;
            ev[j] = e; mx = fmaxf(mx, e);
        }
        float ss = 0.f, acc = 0.f;
        #pragma unroll
        for (int j = 0; j < 6; ++j) {
            float ex = __expf(ev[j] - mx);
            ss += ex; acc += ex * hj[j];
        }
        out[(gb0 + bb) * 6 + ii] = acc / ss + b2[0];
    }
}

extern "C" void kernel_launch(void* const* d_in, const int* in_sizes, int n_in,
                              void* d_out, int out_size, void* d_ws, size_t ws_size,
                              hipStream_t stream) {
    const float* org_obs    = (const float*)d_in[0];
    const float* node_emb   = (const float*)d_in[1];
    const float* subst      = (const float*)d_in[2];
    const int*   sub_choice = (const int*)d_in[3];
    const int*   sub_map    = (const int*)d_in[4];
    const float* Wproj      = (const float*)d_in[5];
    const float* bproj      = (const float*)d_in[6];
    const float* W1         = (const float*)d_in[7];
    const float* a_src1     = (const float*)d_in[8];
    const float* a_dst1     = (const float*)d_in[9];
    const float* b1         = (const float*)d_in[10];
    const float* W2         = (const float*)d_in[11];
    const float* a_src2     = (const float*)d_in[12];
    const float* a_dst2     = (const float*)d_in[13];
    const float* b2         = (const float*)d_in[14];

    ushort_t* WfT   = (ushort_t*)((char*)d_ws + WS_WFT);
    ushort_t* W1cT  = (ushort_t*)((char*)d_ws + WS_W1CT);
    float*    biasw = (float*)((char*)d_ws + WS_BIAS);

    hipLaunchKernelGGL(k_prep, dim3(393), dim3(256), 0, stream,
                       Wproj, bproj, W1, a_src1, a_dst1, WfT, W1cT, biasw);
    hipLaunchKernelGGL(k_main, dim3(BB / TB), dim3(NTHR), 0, stream,
                       org_obs, node_emb, subst, sub_choice, sub_map,
                       WfT, W1cT, biasw, b1, W2, a_src2, a_dst2, b2,
                       (float*)d_out);
}